// Round 15
// baseline (261.045 us; speedup 1.0000x reference)
//
#include <hip/hip_runtime.h>
#include <hip/hip_bf16.h>
#include <hip/hip_fp16.h>
#include <math.h>

#define N_GRAPHS 64
#define N_CLASSES 10
#define FIXSCALE 262144.0f  // 2^18 fixed-point scale for packed degree sum (24-bit field)
#define MAXDEG 64           // deg ~ Poisson(16): P(deg>=64) ~ 1e-18/node — safe

typedef __hip_bfloat16 bf16;

// edge record: row (16 high bits) | fp16 sigmoid(P) (16 low bits). Zero record == no-op.
__device__ __forceinline__ unsigned int pack_edge(int r, float s) {
    return ((unsigned int)r << 16) | (unsigned int)__half_as_ushort(__float2half(s));
}

// ---------------- init: zero packed hist + pool buffers; fold Wc = W3@Wl, bc = b3@Wl+bl ----------------
__global__ void init_k(unsigned int* __restrict__ packed,
                       float* __restrict__ sums, float* __restrict__ cntG,
                       const float* __restrict__ W3, const float* __restrict__ b3,
                       const float* __restrict__ Wl, const float* __restrict__ bl,
                       float* __restrict__ Wc, float* __restrict__ bc, int n) {
    int i = blockIdx.x * 256 + threadIdx.x;
    if (i < n) packed[i] = 0u;
    if (i < N_GRAPHS * 64) sums[i] = 0.0f;
    if (i < N_GRAPHS) cntG[i] = 0.0f;
    if (i < 64 * N_CLASSES) {
        int k = i / N_CLASSES, c = i % N_CLASSES;
        float acc = 0.0f;
        for (int m = 0; m < 64; ++m) acc += W3[k * 64 + m] * Wl[m * N_CLASSES + c];
        Wc[i] = acc;
    }
    if (i < N_CLASSES) {
        float acc = bl[i];
        for (int m = 0; m < 64; ++m) acc += b3[m] * Wl[m * N_CLASSES + i];
        bc[i] = acc;
    }
}

// ---------------- hist + direct ELL scatter, 4 edges/thread ----------------
// One u32 atomic per edge: count<<24 | fix18(sigmoid). Returned old count = this
// edge's rank -> write the record straight into ell[col*MAXDEG + rank].
// 4 independent atomic->store chains per thread hide the L2 RMW latency
// (round 14: 1 chain/thread => VALUBusy 1.8%, pure latency stall).
__global__ void hist_k(const float* __restrict__ P, const int* __restrict__ row,
                       const int* __restrict__ col,
                       unsigned int* __restrict__ packed,
                       unsigned int* __restrict__ ell, int E) {
    int t4 = blockIdx.x * 256 + threadIdx.x;
    int e0 = t4 * 4;
    if (e0 + 4 <= E) {
        float4 p4 = *(const float4*)(P + e0);
        int4 r4 = *(const int4*)(row + e0);
        int4 c4 = *(const int4*)(col + e0);
        float s0 = 1.0f / (1.0f + expf(-p4.x));
        float s1 = 1.0f / (1.0f + expf(-p4.y));
        float s2 = 1.0f / (1.0f + expf(-p4.z));
        float s3 = 1.0f / (1.0f + expf(-p4.w));
        unsigned int o0 = atomicAdd(&packed[c4.x], (1u << 24) | (unsigned int)(s0 * FIXSCALE + 0.5f));
        unsigned int o1 = atomicAdd(&packed[c4.y], (1u << 24) | (unsigned int)(s1 * FIXSCALE + 0.5f));
        unsigned int o2 = atomicAdd(&packed[c4.z], (1u << 24) | (unsigned int)(s2 * FIXSCALE + 0.5f));
        unsigned int o3 = atomicAdd(&packed[c4.w], (1u << 24) | (unsigned int)(s3 * FIXSCALE + 0.5f));
        unsigned int k0 = o0 >> 24, k1 = o1 >> 24, k2 = o2 >> 24, k3 = o3 >> 24;
        if (k0 < MAXDEG) ell[c4.x * MAXDEG + k0] = pack_edge(r4.x, s0);
        if (k1 < MAXDEG) ell[c4.y * MAXDEG + k1] = pack_edge(r4.y, s1);
        if (k2 < MAXDEG) ell[c4.z * MAXDEG + k2] = pack_edge(r4.z, s2);
        if (k3 < MAXDEG) ell[c4.w * MAXDEG + k3] = pack_edge(r4.w, s3);
    } else {
        for (int e = e0; e < E; ++e) {
            float s = 1.0f / (1.0f + expf(-P[e]));
            unsigned int v = (1u << 24) | (unsigned int)(s * FIXSCALE + 0.5f);
            unsigned int old = atomicAdd(&packed[col[e]], v);
            unsigned int rank = old >> 24;
            if (rank < MAXDEG) ell[col[e] * MAXDEG + rank] = pack_edge(row[e], s);
        }
    }
}

// ---------------- dis, xg = bf16(dis*x), and ELL tail zero-pad in one pass ----------------
// Zero-pads only slots [cnt, roundup16(cnt)) (<=15 per node) so the agg loop can
// run branch-free 16-wide batches — replaces zeroing the whole 12.8 MB table.
__global__ void disxg_k(const unsigned int* __restrict__ packed,
                        const float* __restrict__ x,
                        float* __restrict__ dis, bf16* __restrict__ xg,
                        unsigned int* __restrict__ ell, int n) {
    int i = blockIdx.x * 256 + threadIdx.x;
    if (i < n * 64) {
        int node = i >> 6;
        int lane = i & 63;
        unsigned int pk = packed[node];  // same word across the node's 64 lanes: cache-hot
        float deg = 1.0f + (float)(pk & 0xFFFFFFu) * (1.0f / FIXSCALE);
        float dv = 1.0f / sqrtf(deg);
        xg[i] = __float2bfloat16(x[i] * dv);
        if (lane == 0) dis[node] = dv;
        int cnt = (int)(pk >> 24);
        if (cnt > MAXDEG) cnt = MAXDEG;
        int pad = ((cnt + 15) & ~15) - cnt;  // 0..15
        if (lane < pad) ell[node * MAXDEG + cnt + lane] = 0u;
    }
}

__device__ __forceinline__ float edge_term(unsigned int v, const bf16* g, int lane) {
    int r = (int)(v >> 16);
    float s = __half2float(__ushort_as_half((unsigned short)(v & 0xFFFFu)));
    return s * __bfloat162float(g[r * 64 + lane]);
}

// ---------------- fused layer on the dis-scaled table g = dis*h ----------------
// acc = dis_c * (g[node] + sum_e s_e * g[row_e])  (== reference agg exactly)
// One node per wave, wave-uniform node: ELL row streams in as scalar
// s_load_dwordx8 pairs; 16 gathers in flight (zero-padded to multiples of 16,
// zero record contributes exactly 0). MODE 1: W in LDS, readlane-GEMM epilogue,
// writes g_next = dis*relu(W*acc+b). MODE 0: pure agg, f32 out for pooling.
template <int MODE>
__global__ __launch_bounds__(256) void agg_mm_k(const bf16* __restrict__ g,
                                                const unsigned int* __restrict__ ell,
                                                const unsigned int* __restrict__ packed,
                                                const float* __restrict__ dis,
                                                const float* __restrict__ W,
                                                const float* __restrict__ b,
                                                float* __restrict__ out,
                                                bf16* __restrict__ out_bf, int n) {
    __shared__ float Wlds[MODE ? 64 * 64 : 1];
    int tid = threadIdx.x;
    if (MODE == 1) {
        for (int i = tid; i < 64 * 64; i += 256) Wlds[i] = W[i];
        __syncthreads();
    }
    int node = __builtin_amdgcn_readfirstlane(blockIdx.x * 4 + (tid >> 6));
    if (node >= n) return;
    int lane = tid & 63;

    float bv = (MODE == 1) ? b[lane] : 0.0f;
    float d = dis[node];
    int cnt = (int)(packed[node] >> 24);
    if (cnt > MAXDEG) cnt = MAXDEG;
    int cnt16 = (cnt + 15) & ~15;  // tail slots zeroed by disxg_k
    float acc = __bfloat162float(g[node * 64 + lane]);  // self loop: dis*h[node]
    const unsigned int* rowp = ell + node * MAXDEG;

    float a[16];
#pragma unroll
    for (int t = 0; t < 16; ++t) a[t] = 0.0f;
    for (int j = 0; j < cnt16; j += 16) {  // uniform: 2x s_load_dwordx8
        unsigned int v[16];
#pragma unroll
        for (int t = 0; t < 16; ++t) v[t] = rowp[j + t];
#pragma unroll
        for (int t = 0; t < 16; ++t) a[t] += edge_term(v[t], g, lane);
    }
#pragma unroll
    for (int off = 8; off >= 1; off >>= 1)
#pragma unroll
        for (int t = 0; t < off; ++t) a[t] += a[t + off];
    acc += a[0];
    acc *= d;  // apply dis_c once

    if (MODE == 1) {
        float o0 = bv, o1 = 0.f, o2 = 0.f, o3 = 0.f;  // 4-way split FMA chain
#pragma unroll
        for (int k = 0; k < 64; k += 4) {
            float av0 = __int_as_float(__builtin_amdgcn_readlane(__float_as_int(acc), k));
            float av1 = __int_as_float(__builtin_amdgcn_readlane(__float_as_int(acc), k + 1));
            float av2 = __int_as_float(__builtin_amdgcn_readlane(__float_as_int(acc), k + 2));
            float av3 = __int_as_float(__builtin_amdgcn_readlane(__float_as_int(acc), k + 3));
            o0 = fmaf(av0, Wlds[(k + 0) * 64 + lane], o0);
            o1 = fmaf(av1, Wlds[(k + 1) * 64 + lane], o1);
            o2 = fmaf(av2, Wlds[(k + 2) * 64 + lane], o2);
            o3 = fmaf(av3, Wlds[(k + 3) * 64 + lane], o3);
        }
        float o = fmaxf((o0 + o1) + (o2 + o3), 0.0f);
        out_bf[node * 64 + lane] = __float2bfloat16(d * o);  // store g_next = dis*h_next
    } else {
        out[node * 64 + lane] = acc;
    }
}

// ---------------- pooling phase A: segmented partial sums, flush on graph change ----------------
__global__ __launch_bounds__(256) void poolpart_k(const float* __restrict__ h,
                                                  const int* __restrict__ batch,
                                                  float* __restrict__ sums,
                                                  float* __restrict__ cntG, int n) {
    int wave = threadIdx.x >> 6, lane = threadIdx.x & 63;
    int base = blockIdx.x * 128 + wave * 32;
    if (base >= n) return;
    int end = base + 32; if (end > n) end = n;
    int g = batch[base];
    float acc = 0.0f;
    int run = 0;
    for (int i = base; i < end; ++i) {
        int gi = batch[i];
        if (gi != g) {
            atomicAdd(&sums[g * 64 + lane], acc);
            if (lane == 0) atomicAdd(&cntG[g], (float)run);
            g = gi; acc = 0.0f; run = 0;
        }
        acc += h[i * 64 + lane];
        ++run;
    }
    atomicAdd(&sums[g * 64 + lane], acc);
    if (lane == 0) atomicAdd(&cntG[g], (float)run);
}

// ---------------- pooling phase B: mean + folded classifier (Wc, bc) ----------------
__global__ void classify_k(const float* __restrict__ sums, const float* __restrict__ cntG,
                           const float* __restrict__ Wc, const float* __restrict__ bc,
                           float* __restrict__ out) {
    __shared__ float pooled[64];
    int g = blockIdx.x;
    int t = threadIdx.x;  // 64
    float inv = 1.0f / fmaxf(cntG[g], 1.0f);
    pooled[t] = sums[g * 64 + t] * inv;
    __syncthreads();
    if (t < N_CLASSES) {
        float acc = bc[t];
        for (int k = 0; k < 64; ++k) acc += pooled[k] * Wc[k * N_CLASSES + t];
        out[g * N_CLASSES + t] = acc;
    }
}

extern "C" void kernel_launch(void* const* d_in, const int* in_sizes, int n_in,
                              void* d_out, int out_size, void* d_ws, size_t ws_size,
                              hipStream_t stream) {
    const float* x     = (const float*)d_in[0];
    const int*   eidx  = (const int*)d_in[1];
    const int*   batch = (const int*)d_in[2];
    const float* P     = (const float*)d_in[3];
    const float* W1 = (const float*)d_in[4];
    const float* b1 = (const float*)d_in[5];
    const float* W2 = (const float*)d_in[6];
    const float* b2 = (const float*)d_in[7];
    const float* W3 = (const float*)d_in[8];
    const float* b3 = (const float*)d_in[9];
    const float* Wl = (const float*)d_in[10];
    const float* bl = (const float*)d_in[11];
    float* out = (float*)d_out;

    const int N = in_sizes[2];      // 50000
    const int E = in_sizes[3];      // 800000
    const int* row = eidx;
    const int* col = eidx + E;

    // workspace layout
    char* p = (char*)d_ws;
    unsigned int* packed = (unsigned int*)p; p += (size_t)N * 4;
    float* dis      = (float*)p; p += (size_t)N * 4;
    float* sums     = (float*)p; p += (size_t)N_GRAPHS * 64 * 4;
    float* cntG     = (float*)p; p += (size_t)N_GRAPHS * 4;
    float* Wc       = (float*)p; p += (size_t)64 * N_CLASSES * 4;
    float* bc       = (float*)p; p += (size_t)N_CLASSES * 4;
    unsigned int* ell = (unsigned int*)p; p += (size_t)N * MAXDEG * 4;  // 12.8 MB
    float* bufF     = (float*)p; p += (size_t)N * 64 * 4;   // f32 h3 for pooling
    bf16*  xg       = (bf16*)p;  p += (size_t)N * 64 * 2;   // g0 = dis*x; reused as g2
    bf16*  gA       = (bf16*)p;  p += (size_t)N * 64 * 2;   // g1
    bf16*  gB       = xg;  // g2 aliases xg (g0 dead after layer 1)

    dim3 blk(256);
    int nodeG = (N + 255) / 256;           // 196
    int edge4G = (E / 4 + 255) / 256;      // 782
    int bigG  = (N * 64 + 255) / 256;      // 12500

    init_k<<<nodeG, blk, 0, stream>>>(packed, sums, cntG, W3, b3, Wl, bl, Wc, bc, N);
    hist_k<<<edge4G, blk, 0, stream>>>(P, row, col, packed, ell, E);
    disxg_k<<<bigG, blk, 0, stream>>>(packed, x, dis, xg, ell, N);

    int aggG = (N + 3) / 4;  // 1 node per wave, 4 waves/block

    // Layer 1: g1 = dis*relu(agg(x) @ W1 + b1)
    agg_mm_k<1><<<aggG, blk, 0, stream>>>(xg, ell, packed, dis, W1, b1, nullptr, gA, N);
    // Layer 2: g2 = dis*relu(agg(h1) @ W2 + b2)
    agg_mm_k<1><<<aggG, blk, 0, stream>>>(gA, ell, packed, dis, W2, b2, nullptr, gB, N);
    // Layer 3 (pure agg; W3/b3 folded into classifier), f32 out for pooling
    agg_mm_k<0><<<aggG, blk, 0, stream>>>(gB, ell, packed, dis, nullptr, nullptr, bufF, nullptr, N);

    // pool + folded classifier
    int poolG = (N + 127) / 128;
    poolpart_k<<<poolG, blk, 0, stream>>>(bufF, batch, sums, cntG, N);
    classify_k<<<N_GRAPHS, dim3(64), 0, stream>>>(sums, cntG, Wc, bc, out);
}